// Round 9
// baseline (854.173 us; speedup 1.0000x reference)
//
#include <hip/hip_runtime.h>
#include <hip/hip_bf16.h>
#include <math.h>

#define IN_DIM 512
#define HID 1024
#define OUT_D 128
#define NN 32
#define ATT_LEN ((NN + 1) * HID)   // 33792
#define MID_LEN (HID * OUT_D)      // 131072

__device__ __forceinline__ float dot4(float4 a, float4 b) {
    return a.x * b.x + a.y * b.y + a.z * b.z + a.w * b.w;
}

__device__ __forceinline__ float wave_reduce(float v) {
#pragma unroll
    for (int off = 32; off; off >>= 1) v += __shfl_xor(v, off, 64);
    return v;  // all lanes hold the sum
}

// ---------------------------------------------------------------------------
// Kernel 1: q = Wq@x+bq ; K = neighbors@Wk^T+bk ; V = neighbors@Wv^T+bv
// One wave per output row h, 3*1024 waves total. mat: 0=q, 1=K, 2=V.
// ---------------------------------------------------------------------------
__global__ __launch_bounds__(256) void qkv_kernel(
    const float* __restrict__ x, const float* __restrict__ nb,
    const float* __restrict__ Wq, const float* __restrict__ bq,
    const float* __restrict__ Wk, const float* __restrict__ bk,
    const float* __restrict__ Wv, const float* __restrict__ bv,
    float* __restrict__ q, float* __restrict__ K, float* __restrict__ V)
{
    int wid  = (blockIdx.x * 256 + threadIdx.x) >> 6;  // 0..3071
    int lane = threadIdx.x & 63;
    int mat  = wid >> 10;
    int h    = wid & (HID - 1);

    if (mat == 0) {
        const float4* Wr = (const float4*)(Wq + (size_t)h * IN_DIM);
        const float4* xv = (const float4*)x;
        float4 w0 = Wr[lane], w1 = Wr[lane + 64];
        float4 x0 = xv[lane], x1 = xv[lane + 64];
        float s = dot4(w0, x0) + dot4(w1, x1);
        s = wave_reduce(s);
        if (lane == 0) q[h] = s + bq[h];
    } else {
        const float* W = (mat == 1) ? Wk : Wv;
        const float* b = (mat == 1) ? bk : bv;
        float*     Out = (mat == 1) ? K  : V;
        const float4* Wr = (const float4*)(W + (size_t)h * IN_DIM);
        float4 w0 = Wr[lane], w1 = Wr[lane + 64];
        float bh = b[h];
        for (int n = 0; n < NN; ++n) {
            const float4* nv = (const float4*)(nb + (size_t)n * IN_DIM);
            float4 a0 = nv[lane], a1 = nv[lane + 64];
            float s = dot4(w0, a0) + dot4(w1, a1);
            s = wave_reduce(s);
            if (lane == 0) Out[n * HID + h] = s + bh;
        }
    }
}

// ---------------------------------------------------------------------------
// Kernel 2: logits = K@q/sqrt(NN); attend = softmax(logits);
//           att = concat(q, attend[n]*V[n]) -> 33792 floats
// Single block, 1024 threads.
// ---------------------------------------------------------------------------
__global__ __launch_bounds__(1024) void att_kernel(
    const float* __restrict__ q, const float* __restrict__ K,
    const float* __restrict__ V, float* __restrict__ att)
{
    __shared__ float logits_s[NN];
    __shared__ float attend_s[NN];
    int t = threadIdx.x;
    int wv = t >> 6, lane = t & 63;

    // phase A: 16 waves x 2 rows each
#pragma unroll
    for (int rep = 0; rep < 2; ++rep) {
        int n = wv * 2 + rep;
        const float4* Kr = (const float4*)(K + (size_t)n * HID);
        const float4* qv = (const float4*)q;
        float s = 0.f;
#pragma unroll
        for (int j = 0; j < 4; ++j) {
            s += dot4(Kr[lane + 64 * j], qv[lane + 64 * j]);
        }
        s = wave_reduce(s);
        if (lane == 0) logits_s[n] = s * 0.17677669529663687f;  // 1/sqrt(32)
    }
    __syncthreads();

    // phase B: softmax over 32 values in first 32 lanes
    if (t < 32) {
        float v = logits_s[t];
        float m = v;
#pragma unroll
        for (int off = 16; off; off >>= 1) m = fmaxf(m, __shfl_xor(m, off, 32));
        float e = expf(v - m);
        float s = e;
#pragma unroll
        for (int off = 16; off; off >>= 1) s += __shfl_xor(s, off, 32);
        attend_s[t] = e / s;
    }
    __syncthreads();

    // phase C: materialize att
    att[t] = q[t];
#pragma unroll 4
    for (int j = 0; j < NN; ++j) {
        att[HID + j * HID + t] = attend_s[j] * V[j * HID + t];
    }
}

// ---------------------------------------------------------------------------
// Kernel 3: H = relu(Wo @ att + bo)   (1024 x 33792)
// One wave per row; 1024 waves.
// ---------------------------------------------------------------------------
__global__ __launch_bounds__(256) void h_kernel(
    const float* __restrict__ Wo, const float* __restrict__ bo,
    const float* __restrict__ att, float* __restrict__ H)
{
    int wid  = (blockIdx.x * 256 + threadIdx.x) >> 6;  // row 0..1023
    int lane = threadIdx.x & 63;
    const float4* Wr = (const float4*)(Wo + (size_t)wid * ATT_LEN);
    const float4* av = (const float4*)att;
    float s = 0.f;
#pragma unroll 4
    for (int j = 0; j < ATT_LEN / 256; ++j) {  // 132 iters
        s += dot4(Wr[lane + 64 * j], av[lane + 64 * j]);
    }
    s = wave_reduce(s);
    if (lane == 0) H[wid] = fmaxf(s + bo[wid], 0.f);
}

// ---------------------------------------------------------------------------
// Kernel 4: C = tanh(W_ih@H + b_ih + b_hh) + (Wfc@H + bfc) * noise
// One wave per row computes both 1024-dot-products. Also zero-inits x_hat.
// (W_hh unused: h0 == 0, so W_hh@h0 == 0; only b_hh survives.)
// ---------------------------------------------------------------------------
__global__ __launch_bounds__(256) void c_kernel(
    const float* __restrict__ W_ih, const float* __restrict__ b_ih,
    const float* __restrict__ b_hh,
    const float* __restrict__ Wfc, const float* __restrict__ bfc,
    const float* __restrict__ noise, const float* __restrict__ H,
    float* __restrict__ C, float* __restrict__ outC, float* __restrict__ xhat)
{
    int wid  = (blockIdx.x * 256 + threadIdx.x) >> 6;  // row 0..1023
    int lane = threadIdx.x & 63;
    const float4* Wa = (const float4*)(W_ih + (size_t)wid * HID);
    const float4* Wb = (const float4*)(Wfc  + (size_t)wid * HID);
    const float4* hv = (const float4*)H;
    float s1 = 0.f, s2 = 0.f;
#pragma unroll
    for (int j = 0; j < 4; ++j) {
        float4 h4 = hv[lane + 64 * j];
        s1 += dot4(Wa[lane + 64 * j], h4);
        s2 += dot4(Wb[lane + 64 * j], h4);
    }
    s1 = wave_reduce(s1);
    s2 = wave_reduce(s2);
    if (lane == 0) {
        float cm = tanhf(s1 + b_ih[wid] + b_hh[wid]);
        float cd = s2 + bfc[wid];
        float c  = cm + cd * noise[wid];
        C[wid] = c;
        outC[wid] = c;
    }
    if (lane == 1 && wid < OUT_D) xhat[wid] = 0.f;  // accumulator init for k6
}

// ---------------------------------------------------------------------------
// Kernel 5 (dominant): mid = W1 @ C + b1   (131072 x 1024)
// One wave per row, 131072 waves, pure streaming float4.
// ---------------------------------------------------------------------------
__global__ __launch_bounds__(256) void mid_kernel(
    const float* __restrict__ W1, const float* __restrict__ b1,
    const float* __restrict__ C, float* __restrict__ mid)
{
    int wid  = (blockIdx.x * 256 + threadIdx.x) >> 6;  // row 0..131071
    int lane = threadIdx.x & 63;
    const float4* Wr = (const float4*)(W1 + (size_t)wid * HID);
    const float4* cv = (const float4*)C;
    float s = 0.f;
#pragma unroll
    for (int j = 0; j < 4; ++j) {
        s += dot4(Wr[lane + 64 * j], cv[lane + 64 * j]);
    }
    s = wave_reduce(s);
    if (lane == 0) mid[wid] = s + b1[wid];
}

// ---------------------------------------------------------------------------
// Kernel 6: x_hat = W2 @ mid + b2   (128 x 131072)
// 16 chunks per row, block-reduce, atomicAdd into pre-zeroed x_hat.
// ---------------------------------------------------------------------------
__global__ __launch_bounds__(256) void xhat_kernel(
    const float* __restrict__ W2, const float* __restrict__ b2,
    const float* __restrict__ mid, float* __restrict__ xhat)
{
    int r     = blockIdx.x >> 4;   // 0..127
    int chunk = blockIdx.x & 15;   // 0..15
    int t     = threadIdx.x;
    const float4* Wr = (const float4*)(W2 + (size_t)r * MID_LEN);
    const float4* mv = (const float4*)mid;
    int base = chunk * 2048;  // float4 index; chunk = 8192 floats
    float s = 0.f;
#pragma unroll
    for (int j = 0; j < 8; ++j) {
        int i = base + j * 256 + t;
        s += dot4(Wr[i], mv[i]);
    }
    s = wave_reduce(s);
    __shared__ float part[4];
    int lane = t & 63, wv = t >> 6;
    if (lane == 0) part[wv] = s;
    __syncthreads();
    if (t == 0) {
        float tot = part[0] + part[1] + part[2] + part[3];
        if (chunk == 0) tot += b2[r];
        atomicAdd(&xhat[r], tot);
    }
}

// ---------------------------------------------------------------------------
extern "C" void kernel_launch(void* const* d_in, const int* in_sizes, int n_in,
                              void* d_out, int out_size, void* d_ws, size_t ws_size,
                              hipStream_t stream) {
    const float* x     = (const float*)d_in[0];
    const float* nb    = (const float*)d_in[1];
    const float* Wq    = (const float*)d_in[2];
    const float* bq    = (const float*)d_in[3];
    const float* Wk    = (const float*)d_in[4];
    const float* bk    = (const float*)d_in[5];
    const float* Wv    = (const float*)d_in[6];
    const float* bv    = (const float*)d_in[7];
    const float* Wo    = (const float*)d_in[8];
    const float* bo    = (const float*)d_in[9];
    const float* W_ih  = (const float*)d_in[10];
    const float* b_ih  = (const float*)d_in[11];
    // d_in[12] = W_hh (unused: h0 == 0)
    const float* b_hh  = (const float*)d_in[13];
    const float* Wfc   = (const float*)d_in[14];
    const float* bfc   = (const float*)d_in[15];
    const float* W1    = (const float*)d_in[16];
    const float* b1    = (const float*)d_in[17];
    const float* W2    = (const float*)d_in[18];
    const float* b2    = (const float*)d_in[19];
    const float* noise = (const float*)d_in[20];

    float* out   = (float*)d_out;         // [0..1024) = C, [1024..1152) = x_hat
    float* outC  = out;
    float* xhat  = out + HID;

    float* ws = (float*)d_ws;
    float* q   = ws;                       // 1024
    float* K   = q + HID;                  // 32768
    float* V   = K + NN * HID;             // 32768
    float* att = V + NN * HID;             // 33792
    float* H   = att + ATT_LEN;            // 1024
    float* C   = H + HID;                  // 1024
    float* mid = C + HID;                  // 131072

    qkv_kernel<<<768, 256, 0, stream>>>(x, nb, Wq, bq, Wk, bk, Wv, bv, q, K, V);
    att_kernel<<<1, 1024, 0, stream>>>(q, K, V, att);
    h_kernel<<<256, 256, 0, stream>>>(Wo, bo, att, H);
    c_kernel<<<256, 256, 0, stream>>>(W_ih, b_ih, b_hh, Wfc, bfc, noise, H, C, outC, xhat);
    mid_kernel<<<MID_LEN / 4, 256, 0, stream>>>(W1, b1, C, mid);
    xhat_kernel<<<OUT_D * 16, 256, 0, stream>>>(W2, b2, mid, xhat);
}